// Round 4
// baseline (264.539 us; speedup 1.0000x reference)
//
#include <hip/hip_runtime.h>
#include <hip/hip_bf16.h>

// ---- types ----
typedef _Float16 halfx8 __attribute__((ext_vector_type(8)));
typedef _Float16 halfx4 __attribute__((ext_vector_type(4)));
typedef float floatx4 __attribute__((ext_vector_type(4)));

#define GLOBAL_AS __attribute__((address_space(1)))
#define LDS_AS __attribute__((address_space(3)))

// async global->LDS, 16B per lane; LDS dest = wave-uniform base + lane*16
__device__ __forceinline__ void async_copy_16(const _Float16* g, _Float16* l) {
    __builtin_amdgcn_global_load_lds((GLOBAL_AS void*)g, (LDS_AS void*)l, 16, 0, 0);
}

// problem dims
#define PM 16384
#define PD 768
#define PA 51
#define PA_PAD 64

// LDS swizzle scheme (bank-conflict fix, verified R2: SQ_LDS_BANK_CONFLICT=0):
//   LDS[row][c'] holds global k-chunk c' ^ (row&7) (16B chunks).
//   Frag read at (row, kc) uses c' = kc ^ (row&7) -> the 64 lanes of one
//   ds_read_b128 spread uniformly over all 8 bank groups.

// ---- fused converts: x->fp16, We->fp16, Wa(padded)->fp16, zero logits+stats ----
__global__ void convert_all_kernel(const float* __restrict__ x, const float* __restrict__ We,
                                   const float* __restrict__ Wa,
                                   _Float16* __restrict__ x16, _Float16* __restrict__ we16,
                                   _Float16* __restrict__ wa16,
                                   float* __restrict__ logits, float* __restrict__ stats) {
    int b = blockIdx.x, t = threadIdx.x;
    if (b < 12288) {                     // x: 16384*768/4 float4s
        int idx = b * 256 + t;
        float4 v = ((const float4*)x)[idx];
        halfx4 h;
        h[0] = (_Float16)v.x; h[1] = (_Float16)v.y; h[2] = (_Float16)v.z; h[3] = (_Float16)v.w;
        *(halfx4*)(x16 + (size_t)idx * 4) = h;
    } else if (b < 12288 + 576) {        // W_embed: 768*768/4 float4s
        int idx = (b - 12288) * 256 + t;
        float4 v = ((const float4*)We)[idx];
        halfx4 h;
        h[0] = (_Float16)v.x; h[1] = (_Float16)v.y; h[2] = (_Float16)v.z; h[3] = (_Float16)v.w;
        *(halfx4*)(we16 + (size_t)idx * 4) = h;
    } else if (b < 12288 + 624) {        // W_attr padded to [64][768]
        int j = (b - 12288 - 576) * 256 + t;
        halfx4 h;
        if (j < (PA * PD) / 4) {
            float4 v = ((const float4*)Wa)[j];
            h[0] = (_Float16)v.x; h[1] = (_Float16)v.y; h[2] = (_Float16)v.z; h[3] = (_Float16)v.w;
        } else {
            h[0] = (_Float16)0.f; h[1] = (_Float16)0.f; h[2] = (_Float16)0.f; h[3] = (_Float16)0.f;
        }
        *(halfx4*)(wa16 + (size_t)j * 4) = h;
    } else if (b < 12288 + 624 + 816) {  // zero logits: 16384*51/4 = 208896 float4s
        int idx4 = (b - 12288 - 624) * 256 + t;
        ((float4*)logits)[idx4] = (float4){0.f, 0.f, 0.f, 0.f};
    } else {
        if (t < 128) stats[t] = 0.f;
    }
}

// ---- MEGA GEMM: h = x@We^T + b_embed (kept in regs/LDS only), then
//      logits += Wa_slice @ h_tile^T partial contribution via atomics. ----
// 128x128 tile, BK=64, 256 threads (2x2 waves of 64x64), swizzled LDS.
__global__ __launch_bounds__(256, 3) void megagemm_kernel(
    const _Float16* __restrict__ A,    // [16384][768] x_f16
    const _Float16* __restrict__ B,    // [768][768]   we16
    const _Float16* __restrict__ Wa,   // [64][768]    wa16 (padded, zero rows >= 51)
    const float* __restrict__ b_embed, // [768]
    const float* __restrict__ b_attr,  // [51]
    float* __restrict__ logits)        // [16384][51] fp32, pre-zeroed
{
    __shared__ __align__(16) char smem[49152];
    _Float16* As  = (_Float16*)smem;             // [128][64] halves, k-loop
    _Float16* Bs  = (_Float16*)(smem + 16384);   // [128][64] halves, k-loop
    _Float16* Was = (_Float16*)(smem + 32768);   // [64][128] halves, persistent
    _Float16* Hs  = (_Float16*)smem;             // [128][128] halves, epilogue (aliases As+Bs)

    const int tid = threadIdx.x;
    const int wave = tid >> 6;
    const int lane = tid & 63;
    const int quad = lane >> 4;
    const int l16 = lane & 15;
    const int wm = wave >> 1;
    const int wn = wave & 1;

    // XCD-aware swizzle (perf heuristic only): all 768 blocks co-resident at 3/CU.
    int b = blockIdx.x;
    int xcd = b & 7;
    int q = b >> 3;                 // 0..95
    int mt = xcd * 16 + (q & 15);   // 0..127
    int nt = q >> 4;                // 0..5
    const int row0 = mt * 128;
    const int col0 = nt * 128;

    const int r_in = lane >> 3;                 // 0..7 row within 8-row staging group
    const int ksw = ((lane & 7) ^ r_in) * 8;    // swizzled k-offset (halves)

    // ---- stage Wa slice [64 attrs][col0..col0+127] into Was, swizzled ----
    {
        int rl = lane >> 4;          // 0..3 (row within 4-row group)
        int cl = lane & 15;          // dest chunk slot 0..15
        #pragma unroll
        for (int j = 0; j < 4; ++j) {
            int i = wave * 4 + j;    // 0..15 -> rows i*4..i*4+3
            int row = i * 4 + rl;
            int c = cl ^ (row & 7);  // source chunk (16B units of the 128-col slice)
            async_copy_16(Wa + (size_t)row * PD + col0 + c * 8, &Was[i * 512]);
        }
    }

    const _Float16* Ag = A + (size_t)row0 * PD + ksw;
    const _Float16* Bg = B + (size_t)col0 * PD + ksw;

    floatx4 acc[4][4];
    #pragma unroll
    for (int i = 0; i < 4; ++i)
        #pragma unroll
        for (int j = 0; j < 4; ++j)
            acc[i][j] = (floatx4){0.f, 0.f, 0.f, 0.f};

    for (int kt = 0; kt < PD; kt += 64) {
        #pragma unroll
        for (int j = 0; j < 4; ++j) {
            int i = wave * 4 + j;       // 0..15, rows i*8..i*8+7
            async_copy_16(Ag + (size_t)(i * 8 + r_in) * PD + kt, &As[i * 512]);
            async_copy_16(Bg + (size_t)(i * 8 + r_in) * PD + kt, &Bs[i * 512]);
        }
        __syncthreads();
        #pragma unroll
        for (int ks = 0; ks < 2; ++ks) {
            halfx8 af[4], bf[4];
            #pragma unroll
            for (int mi = 0; mi < 4; ++mi)
                af[mi] = *(const halfx8*)&As[(wm * 64 + mi * 16 + l16) * 64 +
                                             (((ks * 4 + quad) ^ (l16 & 7)) << 3)];
            #pragma unroll
            for (int ni = 0; ni < 4; ++ni)
                bf[ni] = *(const halfx8*)&Bs[(wn * 64 + ni * 16 + l16) * 64 +
                                             (((ks * 4 + quad) ^ (l16 & 7)) << 3)];
            #pragma unroll
            for (int mi = 0; mi < 4; ++mi)
                #pragma unroll
                for (int ni = 0; ni < 4; ++ni)
                    acc[mi][ni] = __builtin_amdgcn_mfma_f32_16x16x32_f16(af[mi], bf[ni], acc[mi][ni], 0, 0, 0);
        }
        __syncthreads();
    }

    // ---- epilogue part 1: h tile (with b_embed) -> Hs [row][col], swizzled ----
    // C/D layout: col = l16, row = quad*4 + reg (m89-verified).
    #pragma unroll
    for (int ni = 0; ni < 4; ++ni) {
        int C = wn * 64 + ni * 16 + l16;          // tile col 0..127
        float bv = b_embed[col0 + C];
        int cc = C >> 3;                          // 16B chunk index 0..15
        int co = C & 7;                           // half within chunk
        #pragma unroll
        for (int mi = 0; mi < 4; ++mi) {
            #pragma unroll
            for (int r = 0; r < 4; ++r) {
                int R = wm * 64 + mi * 16 + quad * 4 + r;   // tile row 0..127
                Hs[R * 128 + ((cc ^ (R & 7)) << 3) + co] = (_Float16)(acc[mi][ni][r] + bv);
            }
        }
    }
    __syncthreads();

    // ---- epilogue part 2: logitsT_partial [64 attrs][128 rows] = Was @ Hs^T ----
    // A-frag = Was (m = attr), B-frag = Hs (n = h-row, k = h-col). K2 = 128.
    floatx4 acc2[4][2];     // [m-frag attr][n-frag row]
    #pragma unroll
    for (int i = 0; i < 4; ++i)
        #pragma unroll
        for (int j = 0; j < 2; ++j)
            acc2[i][j] = (floatx4){0.f, 0.f, 0.f, 0.f};

    #pragma unroll
    for (int ks2 = 0; ks2 < 4; ++ks2) {
        halfx8 afr[4], bfr[2];
        #pragma unroll
        for (int mf = 0; mf < 4; ++mf)
            afr[mf] = *(const halfx8*)&Was[(mf * 16 + l16) * 128 +
                                           (((ks2 * 4 + quad) ^ (l16 & 7)) << 3)];
        #pragma unroll
        for (int nf = 0; nf < 2; ++nf)
            bfr[nf] = *(const halfx8*)&Hs[(wave * 32 + nf * 16 + l16) * 128 +
                                          (((ks2 * 4 + quad) ^ (l16 & 7)) << 3)];
        #pragma unroll
        for (int mf = 0; mf < 4; ++mf)
            #pragma unroll
            for (int nf = 0; nf < 2; ++nf)
                acc2[mf][nf] = __builtin_amdgcn_mfma_f32_16x16x32_f16(afr[mf], bfr[nf], acc2[mf][nf], 0, 0, 0);
    }

    // ---- scatter partial logits (fire-and-forget atomics); nt==0 adds b_attr ----
    const bool add_bias = (nt == 0);
    #pragma unroll
    for (int mf = 0; mf < 4; ++mf) {
        #pragma unroll
        for (int nf = 0; nf < 2; ++nf) {
            int grow = row0 + wave * 32 + nf * 16 + l16;
            #pragma unroll
            for (int r = 0; r < 4; ++r) {
                int attr = mf * 16 + quad * 4 + r;     // D row = m = attr
                if (attr < PA) {
                    float v = acc2[mf][nf][r];
                    if (add_bias) v += b_attr[attr];
                    atomicAdd(&logits[(size_t)grow * PA + attr], v);
                }
            }
        }
    }
}

// ------------------- BN stats: per-attr sum / sumsq -------------------
__global__ void bn_stats_kernel(const float* __restrict__ logits, float* __restrict__ stats) {
    __shared__ float s_sum[PA];
    __shared__ float s_ssq[PA];
    int t = threadIdx.x;
    if (t < PA) { s_sum[t] = 0.f; s_ssq[t] = 0.f; }
    __syncthreads();
    int idx4 = blockIdx.x * 256 + t;          // 816*256 = 208896 = 16384*51/4 exact
    float4 v = ((const float4*)logits)[idx4];
    float vals[4] = {v.x, v.y, v.z, v.w};
    int base = idx4 * 4;
    #pragma unroll
    for (int j = 0; j < 4; ++j) {
        int col = (base + j) % PA;            // compiler magic-div
        atomicAdd(&s_sum[col], vals[j]);
        atomicAdd(&s_ssq[col], vals[j] * vals[j]);
    }
    __syncthreads();
    if (t < PA) {
        atomicAdd(&stats[t], s_sum[t]);
        atomicAdd(&stats[64 + t], s_ssq[t]);
    }
}

// ------------------- BN finalize -------------------
__global__ void bn_finalize_kernel(const float* __restrict__ logits,
                                   const float* __restrict__ stats,
                                   const float* __restrict__ gamma,
                                   const float* __restrict__ beta,
                                   float* __restrict__ out, int total) {
    __shared__ float s_scale[PA];
    __shared__ float s_shift[PA];
    int t = threadIdx.x;
    if (t < PA) {
        const float invB = 1.0f / (float)PM;
        float mean = stats[t] * invB;
        float var = stats[64 + t] * invB - mean * mean;
        float inv = rsqrtf(var + 1e-5f);
        float g = gamma[t] * inv;
        s_scale[t] = g;
        s_shift[t] = beta[t] - mean * g;
    }
    __syncthreads();
    int idx = blockIdx.x * 256 + t;
    if (idx < total) {
        int col = idx % PA;
        out[idx] = logits[idx] * s_scale[col] + s_shift[col];
    }
}

// ------------------- launch -------------------
extern "C" void kernel_launch(void* const* d_in, const int* in_sizes, int n_in,
                              void* d_out, int out_size, void* d_ws, size_t ws_size,
                              hipStream_t stream) {
    const float* x       = (const float*)d_in[0];
    const float* W_embed = (const float*)d_in[1];
    const float* b_embed = (const float*)d_in[2];
    const float* W_attr  = (const float*)d_in[3];
    const float* b_attr  = (const float*)d_in[4];
    const float* gamma   = (const float*)d_in[5];
    const float* beta    = (const float*)d_in[6];
    float* out = (float*)d_out;

    char* ws = (char*)d_ws;
    _Float16* x_f16  = (_Float16*)(ws);                    // 16384*768*2 = 25165824
    _Float16* we16   = (_Float16*)(ws + 25165824);         // 768*768*2   = 1179648
    _Float16* wa16   = (_Float16*)(ws + 26345472);         // 64*768*2    = 98304
    float*    logits = (float*)   (ws + 26443776);         // 16384*51*4  = 3342336
    float*    stats  = (float*)   (ws + 29786112);         // 128*4       = 512

    convert_all_kernel<<<13729, 256, 0, stream>>>(x, W_embed, W_attr, x_f16, we16, wa16, logits, stats);
    megagemm_kernel<<<768, 256, 0, stream>>>(x_f16, we16, wa16, b_embed, b_attr, logits);
    bn_stats_kernel<<<816, 256, 0, stream>>>(logits, stats);
    bn_finalize_kernel<<<3264, 256, 0, stream>>>(logits, stats, gamma, beta, out, PM * PA);
}

// Round 5
// 152.208 us; speedup vs baseline: 1.7380x; 1.7380x over previous
//
#include <hip/hip_runtime.h>
#include <hip/hip_bf16.h>

// ---- types ----
typedef _Float16 halfx8 __attribute__((ext_vector_type(8)));
typedef _Float16 halfx4 __attribute__((ext_vector_type(4)));
typedef float floatx4 __attribute__((ext_vector_type(4)));

#define GLOBAL_AS __attribute__((address_space(1)))
#define LDS_AS __attribute__((address_space(3)))

// async global->LDS, 16B per lane; LDS dest = wave-uniform base + lane*16
__device__ __forceinline__ void async_copy_16(const void* g, void* l) {
    __builtin_amdgcn_global_load_lds((GLOBAL_AS void*)g, (LDS_AS void*)l, 16, 0, 0);
}

// problem dims
#define PM 16384
#define PD 768
#define PA 51

// Math identity: logits = x @ (Wa@We)^T + (Wa@b_embed + b_attr).
// h = x@We^T + b_embed is NOT an output -> never materialized.

// ---- precompute: W_comb[64][768] fp16 (rows>=51 zeroed), b_comb[64], zero stats ----
// blocks 0..50: W_comb row b (fp32 math, coalesced We reads, 4 cols/thread)
// block 51: zero pad rows + stats   block 52: b_comb
__global__ __launch_bounds__(192) void precompute_kernel(
    const float* __restrict__ We, const float* __restrict__ Wa,
    const float* __restrict__ b_embed, const float* __restrict__ b_attr,
    _Float16* __restrict__ wc16, float* __restrict__ bc, float* __restrict__ stats)
{
    int b = blockIdx.x, t = threadIdx.x;
    if (b < PA) {
        int d0 = t * 4;                        // 192 threads * 4 = 768 cols
        const float* war = Wa + (size_t)b * PD;
        float a0 = 0.f, a1 = 0.f, a2 = 0.f, a3 = 0.f;
        #pragma unroll 8
        for (int k = 0; k < PD; ++k) {
            float w = war[k];                  // block-uniform -> s_load
            floatx4 v = *(const floatx4*)(We + (size_t)k * PD + d0);
            a0 += w * v[0]; a1 += w * v[1]; a2 += w * v[2]; a3 += w * v[3];
        }
        halfx4 h;
        h[0] = (_Float16)a0; h[1] = (_Float16)a1; h[2] = (_Float16)a2; h[3] = (_Float16)a3;
        *(halfx4*)(wc16 + (size_t)b * PD + d0) = h;
    } else if (b == PA) {
        // zero rows 51..63 (13*768 = 9984 halves = 1248 halfx8) -- ws is re-poisoned!
        halfx8 z;
        #pragma unroll
        for (int j = 0; j < 8; ++j) z[j] = (_Float16)0.f;
        for (int i = t; i < 1248; i += 192)
            *(halfx8*)(wc16 + PA * PD + i * 8) = z;
        if (t < 128) stats[t] = 0.f;
    } else {
        if (t < PA) {
            const float* war = Wa + (size_t)t * PD;
            float acc = 0.f;
            #pragma unroll 4
            for (int k = 0; k < PD; k += 4) {
                floatx4 w = *(const floatx4*)(war + k);
                floatx4 e = *(const floatx4*)(b_embed + k);
                acc += w[0] * e[0] + w[1] * e[1] + w[2] * e[2] + w[3] * e[3];
            }
            bc[t] = acc + b_attr[t];
        }
    }
}

// ---- skinny GEMM: logits = x @ W_comb^T + b_comb, fused per-attr sum/sumsq ----
// 64 rows x 64 attrs (51 valid) per block, BK=64, 256 threads / 4 waves (16 rows each).
// A staged as RAW fp32 via global_load_lds (async path preserved), cvt fp16 at
// LDS->reg. XOR swizzle (verified 0-conflict R2): LDS[row][slot], slot = chunk ^ (row&7).
__global__ __launch_bounds__(256) void skinny_gemm_kernel(
    const float* __restrict__ X,        // [16384][768] fp32
    const _Float16* __restrict__ Wc,    // [64][768] fp16, rows >= 51 zero
    const float* __restrict__ bc,       // [64] combined bias
    float* __restrict__ logits,         // [16384][51]
    float* __restrict__ stats)          // [0..50]=sum, [64..114]=sumsq
{
    __shared__ float As[64 * 64];       // fp32 tile; 16 chunks (16B=4 floats) per row
    __shared__ _Float16 Bs[64 * 64];    // fp16 tile; 8 chunks (16B=8 halves) per row
    __shared__ float s_sum[64];
    __shared__ float s_ssq[64];

    const int tid = threadIdx.x;
    const int wave = tid >> 6;
    const int lane = tid & 63;
    const int quad = lane >> 4;
    const int l16 = lane & 15;
    const int row0 = blockIdx.x * 64;

    if (tid < 64) { s_sum[tid] = 0.f; s_ssq[tid] = 0.f; }

    const int a_r  = lane >> 4;         // A staging: 4 rows per async group
    const int a_sl = lane & 15;         //   dest slot 0..15
    const int b_r  = lane >> 3;         // B staging: 8 rows per async group
    const int b_sl = lane & 7;          //   dest slot 0..7

    floatx4 acc[4];
    #pragma unroll
    for (int j = 0; j < 4; ++j) acc[j] = (floatx4){0.f, 0.f, 0.f, 0.f};

    for (int kt = 0; kt < PD; kt += 64) {
        // A: 16 asyncs (4/wave), each 1KB = 4 rows x 256B (xor-permuted within row)
        #pragma unroll
        for (int j = 0; j < 4; ++j) {
            int g = wave * 4 + j;            // 0..15
            int r = g * 4 + a_r;             // 0..63
            int c = a_sl ^ (r & 7);          // source 16B chunk (4 floats)
            async_copy_16(X + (size_t)(row0 + r) * PD + kt + c * 4, &As[g * 256]);
        }
        // B: 8 asyncs (2/wave), each 1KB = 8 rows x 128B
        #pragma unroll
        for (int j = 0; j < 2; ++j) {
            int g = wave * 2 + j;            // 0..7
            int r = g * 8 + b_r;             // 0..63
            int c = b_sl ^ (r & 7);          // source 16B chunk (8 halves)
            async_copy_16(Wc + (size_t)r * PD + kt + c * 8, &Bs[g * 512]);
        }
        __syncthreads();
        #pragma unroll
        for (int ks = 0; ks < 2; ++ks) {
            // A-frag: m = l16 (row wave*16+l16), k = quad*8+j within this 32-step
            int r = wave * 16 + l16;
            int c0 = ks * 8 + quad * 2;
            floatx4 p0 = *(const floatx4*)&As[r * 64 + ((c0 ^ (l16 & 7)) << 2)];
            floatx4 p1 = *(const floatx4*)&As[r * 64 + (((c0 + 1) ^ (l16 & 7)) << 2)];
            halfx8 af;
            af[0] = (_Float16)p0[0]; af[1] = (_Float16)p0[1];
            af[2] = (_Float16)p0[2]; af[3] = (_Float16)p0[3];
            af[4] = (_Float16)p1[0]; af[5] = (_Float16)p1[1];
            af[6] = (_Float16)p1[2]; af[7] = (_Float16)p1[3];
            halfx8 bf[4];
            #pragma unroll
            for (int ni = 0; ni < 4; ++ni)
                bf[ni] = *(const halfx8*)&Bs[(ni * 16 + l16) * 64 +
                                             (((ks * 4 + quad) ^ (l16 & 7)) << 3)];
            #pragma unroll
            for (int ni = 0; ni < 4; ++ni)
                acc[ni] = __builtin_amdgcn_mfma_f32_16x16x32_f16(af, bf[ni], acc[ni], 0, 0, 0);
        }
        __syncthreads();
    }

    // epilogue: D col (n) = attr = ni*16 + l16, D row (m) = quad*4 + r  (m89-verified)
    #pragma unroll
    for (int ni = 0; ni < 4; ++ni) {
        int col = ni * 16 + l16;
        if (col < PA) {
            float bv = bc[col];
            float ps = 0.f, pss = 0.f;
            int rowb = row0 + wave * 16 + quad * 4;
            #pragma unroll
            for (int r = 0; r < 4; ++r) {
                float v = acc[ni][r] + bv;
                logits[(size_t)(rowb + r) * PA + col] = v;
                ps += v; pss += v * v;
            }
            atomicAdd(&s_sum[col], ps);
            atomicAdd(&s_ssq[col], pss);
        }
    }
    __syncthreads();
    if (tid < PA) {
        atomicAdd(&stats[tid], s_sum[tid]);
        atomicAdd(&stats[64 + tid], s_ssq[tid]);
    }
}

// ------------------- BN finalize -------------------
__global__ void bn_finalize_kernel(const float* __restrict__ logits,
                                   const float* __restrict__ stats,
                                   const float* __restrict__ gamma,
                                   const float* __restrict__ beta,
                                   float* __restrict__ out, int total) {
    __shared__ float s_scale[PA];
    __shared__ float s_shift[PA];
    int t = threadIdx.x;
    if (t < PA) {
        const float invB = 1.0f / (float)PM;
        float mean = stats[t] * invB;
        float var = stats[64 + t] * invB - mean * mean;
        float inv = rsqrtf(var + 1e-5f);
        float g = gamma[t] * inv;
        s_scale[t] = g;
        s_shift[t] = beta[t] - mean * g;
    }
    __syncthreads();
    int idx = blockIdx.x * 256 + t;
    if (idx < total) {
        int col = idx % PA;
        out[idx] = logits[idx] * s_scale[col] + s_shift[col];
    }
}

// ------------------- launch -------------------
extern "C" void kernel_launch(void* const* d_in, const int* in_sizes, int n_in,
                              void* d_out, int out_size, void* d_ws, size_t ws_size,
                              hipStream_t stream) {
    const float* x       = (const float*)d_in[0];
    const float* W_embed = (const float*)d_in[1];
    const float* b_embed = (const float*)d_in[2];
    const float* W_attr  = (const float*)d_in[3];
    const float* b_attr  = (const float*)d_in[4];
    const float* gamma   = (const float*)d_in[5];
    const float* beta    = (const float*)d_in[6];
    float* out = (float*)d_out;

    char* ws = (char*)d_ws;
    _Float16* wc16   = (_Float16*)(ws);                // 64*768*2 = 98304
    float*    bc     = (float*)   (ws + 98304);        // 64*4     = 256
    float*    stats  = (float*)   (ws + 98560);        // 128*4    = 512
    float*    logits = (float*)   (ws + 99072);        // 16384*51*4 = 3342336

    precompute_kernel<<<53, 192, 0, stream>>>(W_embed, W_attr, b_embed, b_attr, wc16, bc, stats);
    skinny_gemm_kernel<<<256, 256, 0, stream>>>(x, wc16, bc, logits, stats);
    bn_finalize_kernel<<<3264, 256, 0, stream>>>(logits, stats, gamma, beta, out, PM * PA);
}

// Round 6
// 131.324 us; speedup vs baseline: 2.0144x; 1.1590x over previous
//
#include <hip/hip_runtime.h>
#include <hip/hip_bf16.h>

// ---- types ----
typedef _Float16 halfx8 __attribute__((ext_vector_type(8)));
typedef _Float16 halfx4 __attribute__((ext_vector_type(4)));
typedef float floatx4 __attribute__((ext_vector_type(4)));

#define GLOBAL_AS __attribute__((address_space(1)))
#define LDS_AS __attribute__((address_space(3)))

// async global->LDS, 16B per lane; LDS dest = wave-uniform base + lane*16
__device__ __forceinline__ void async_copy_16(const void* g, void* l) {
    __builtin_amdgcn_global_load_lds((GLOBAL_AS void*)g, (LDS_AS void*)l, 16, 0, 0);
}

// problem dims
#define PM 16384
#define PD 768
#define PA 51

// Math identity (verified R5): logits = x @ (Wa@We)^T + (Wa@b_embed + b_attr).
// h is never materialized.

// ---- init: zero wc32[64][768] + stats, compute b_comb ----
__global__ __launch_bounds__(256) void init_kernel(
    const float* __restrict__ Wa, const float* __restrict__ b_embed,
    const float* __restrict__ b_attr,
    float* __restrict__ wc32, float* __restrict__ bc, float* __restrict__ stats)
{
    int b = blockIdx.x, t = threadIdx.x;
    if (b < 12) {                        // zero wc32: 49152 floats = 12288 float4
        #pragma unroll
        for (int j = 0; j < 4; ++j)
            ((float4*)wc32)[b * 1024 + j * 256 + t] = (float4){0.f, 0.f, 0.f, 0.f};
    } else {
        if (t < 128) stats[t] = 0.f;
        // bc[a] = dot(Wa[a], b_embed) + b_attr[a]; 4 threads per attr
        __shared__ float red[256];
        int a = t & 63, qtr = t >> 6;
        float partial = 0.f;
        if (a < PA) {
            const float* war = Wa + (size_t)a * PD + qtr * 192;
            const float* ber = b_embed + qtr * 192;
            #pragma unroll 4
            for (int k = 0; k < 192; k += 4) {
                floatx4 w = *(const floatx4*)(war + k);
                floatx4 e = *(const floatx4*)(ber + k);
                partial += w[0]*e[0] + w[1]*e[1] + w[2]*e[2] + w[3]*e[3];
            }
        }
        red[t] = partial;
        __syncthreads();
        if (t < PA)
            bc[t] = red[t] + red[64 + t] + red[128 + t] + red[192 + t] + b_attr[t];
    }
}

// ---- W_comb: wc32[a][d] += sum_k Wa[a][k]*We[k][d]  (K-split atomic GEMM) ----
// grid 192 = 12 N-chunks (64 cols) x 16 K-chunks (48). We read exactly once.
__global__ __launch_bounds__(256) void wcomb_kernel(
    const float* __restrict__ We, const float* __restrict__ Wa,
    float* __restrict__ wc32)
{
    __shared__ float WeS[48 * 64];   // [k][d] slice
    __shared__ float WaS[51 * 48];   // [a][k] slice
    const int b = blockIdx.x;
    const int kc = b & 15;           // K-chunk 0..15
    const int nc = b >> 4;           // N-chunk 0..11
    const int k0 = kc * 48, d0 = nc * 64;
    const int t = threadIdx.x;

    // stage We slice: 768 float4s, coalesced (16 lanes span one 64-col row)
    #pragma unroll
    for (int j = 0; j < 3; ++j) {
        int idx4 = j * 256 + t;
        int r = idx4 >> 4, c4 = idx4 & 15;
        *(floatx4*)&WeS[r * 64 + c4 * 4] =
            *(const floatx4*)(We + (size_t)(k0 + r) * PD + d0 + c4 * 4);
    }
    // stage Wa slice: 612 float4s
    for (int idx4 = t; idx4 < 612; idx4 += 256) {
        int r = idx4 / 12, c4 = idx4 % 12;
        *(floatx4*)&WaS[r * 48 + c4 * 4] =
            *(const floatx4*)(Wa + (size_t)r * PD + k0 + c4 * 4);
    }
    __syncthreads();

    const int c = t & 63;            // my output column (lane-consecutive)
    const int ag = t >> 6;           // my attr group (wave-uniform)

    float we[48];                    // hoist my We column into registers
    #pragma unroll
    for (int k = 0; k < 48; ++k) we[k] = WeS[k * 64 + c];

    #pragma unroll
    for (int i = 0; i < 13; ++i) {
        int a = ag + i * 4;          // wave-uniform -> WaS reads broadcast
        if (a < PA) {
            float acc = 0.f;
            #pragma unroll
            for (int k4 = 0; k4 < 12; ++k4) {
                floatx4 wa = *(const floatx4*)&WaS[a * 48 + k4 * 4];
                acc += wa[0] * we[k4*4] + wa[1] * we[k4*4+1]
                     + wa[2] * we[k4*4+2] + wa[3] * we[k4*4+3];
            }
            atomicAdd(&wc32[(size_t)a * PD + d0 + c], acc);   // coalesced fp32 atomic
        }
    }
}

// ---- skinny GEMM: logits = x @ W_comb^T + b_comb, fused per-attr sum/sumsq ----
// 32 rows x 64 attrs per block -> 512 blocks (2/CU for barrier-drain overlap).
// 256 thr / 4 waves: wave w handles rows (w&1)*16.., attrs (w>>1)*32.. (2 frags).
// Both A (x) and B (wc32) staged as RAW fp32 via async global_load_lds,
// converted fp16 at LDS->reg. XOR swizzle (R2-verified 0-conflict).
__global__ __launch_bounds__(256) void skinny_gemm_kernel(
    const float* __restrict__ X,        // [16384][768] fp32
    const float* __restrict__ Wc,       // [64][768] fp32, rows >= 51 zero
    const float* __restrict__ bc,       // [64] combined bias
    float* __restrict__ logits,         // [16384][51]
    float* __restrict__ stats)          // [0..50]=sum, [64..114]=sumsq
{
    __shared__ float As[32 * 64];       // fp32; 16 16B-chunks (4 floats) per row
    __shared__ float Bs[64 * 64];       // fp32; 16 16B-chunks per row
    __shared__ float s_sum[64];
    __shared__ float s_ssq[64];

    const int tid = threadIdx.x;
    const int wave = tid >> 6;
    const int lane = tid & 63;
    const int quad = lane >> 4;
    const int l16 = lane & 15;
    const int wr = wave & 1;            // row half
    const int wn = wave >> 1;           // attr half
    const int row0 = blockIdx.x * 32;

    if (tid < 64) { s_sum[tid] = 0.f; s_ssq[tid] = 0.f; }

    const int g_r  = lane >> 4;         // 4 rows per 1KB async group
    const int g_sl = lane & 15;         // dest chunk slot 0..15

    floatx4 acc[2];
    acc[0] = (floatx4){0.f, 0.f, 0.f, 0.f};
    acc[1] = (floatx4){0.f, 0.f, 0.f, 0.f};

    for (int kt = 0; kt < PD; kt += 64) {
        // A: 8 asyncs (2/wave): rows 0..31
        #pragma unroll
        for (int j = 0; j < 2; ++j) {
            int g = wave * 2 + j;            // 0..7
            int r = g * 4 + g_r;             // 0..31
            int csrc = g_sl ^ (r & 7);
            async_copy_16(X + (size_t)(row0 + r) * PD + kt + csrc * 4, &As[g * 256]);
        }
        // B: 16 asyncs (4/wave): rows 0..63
        #pragma unroll
        for (int j = 0; j < 4; ++j) {
            int g = wave * 4 + j;            // 0..15
            int r = g * 4 + g_r;             // 0..63
            int csrc = g_sl ^ (r & 7);
            async_copy_16(Wc + (size_t)r * PD + kt + csrc * 4, &Bs[g * 256]);
        }
        __syncthreads();
        #pragma unroll
        for (int ks = 0; ks < 2; ++ks) {
            int c0 = ks * 8 + quad * 2;      // first 4-float chunk of my k-octet
            int sw = l16 & 7;
            // A-frag: m = l16 -> tile row wr*16+l16; k = ks*32+quad*8+j
            int rA = wr * 16 + l16;
            floatx4 p0 = *(const floatx4*)&As[rA * 64 + ((c0 ^ sw) << 2)];
            floatx4 p1 = *(const floatx4*)&As[rA * 64 + (((c0 + 1) ^ sw) << 2)];
            halfx8 af;
            af[0] = (_Float16)p0[0]; af[1] = (_Float16)p0[1];
            af[2] = (_Float16)p0[2]; af[3] = (_Float16)p0[3];
            af[4] = (_Float16)p1[0]; af[5] = (_Float16)p1[1];
            af[6] = (_Float16)p1[2]; af[7] = (_Float16)p1[3];
            #pragma unroll
            for (int ni = 0; ni < 2; ++ni) {
                int rB = wn * 32 + ni * 16 + l16;
                floatx4 q0 = *(const floatx4*)&Bs[rB * 64 + ((c0 ^ sw) << 2)];
                floatx4 q1 = *(const floatx4*)&Bs[rB * 64 + (((c0 + 1) ^ sw) << 2)];
                halfx8 bf;
                bf[0] = (_Float16)q0[0]; bf[1] = (_Float16)q0[1];
                bf[2] = (_Float16)q0[2]; bf[3] = (_Float16)q0[3];
                bf[4] = (_Float16)q1[0]; bf[5] = (_Float16)q1[1];
                bf[6] = (_Float16)q1[2]; bf[7] = (_Float16)q1[3];
                acc[ni] = __builtin_amdgcn_mfma_f32_16x16x32_f16(af, bf, acc[ni], 0, 0, 0);
            }
        }
        __syncthreads();
    }

    // epilogue: D col (n) = attr, D row (m) = quad*4 + r  (m89-verified layout)
    #pragma unroll
    for (int ni = 0; ni < 2; ++ni) {
        int col = wn * 32 + ni * 16 + l16;
        if (col < PA) {
            float bv = bc[col];
            float ps = 0.f, pss = 0.f;
            int rowb = row0 + wr * 16 + quad * 4;
            #pragma unroll
            for (int r = 0; r < 4; ++r) {
                float v = acc[ni][r] + bv;
                logits[(size_t)(rowb + r) * PA + col] = v;
                ps += v; pss += v * v;
            }
            atomicAdd(&s_sum[col], ps);
            atomicAdd(&s_ssq[col], pss);
        }
    }
    __syncthreads();
    if (tid < PA) {
        atomicAdd(&stats[tid], s_sum[tid]);
        atomicAdd(&stats[64 + tid], s_ssq[tid]);
    }
}

// ------------------- BN finalize -------------------
__global__ void bn_finalize_kernel(const float* __restrict__ logits,
                                   const float* __restrict__ stats,
                                   const float* __restrict__ gamma,
                                   const float* __restrict__ beta,
                                   float* __restrict__ out, int total) {
    __shared__ float s_scale[PA];
    __shared__ float s_shift[PA];
    int t = threadIdx.x;
    if (t < PA) {
        const float invB = 1.0f / (float)PM;
        float mean = stats[t] * invB;
        float var = stats[64 + t] * invB - mean * mean;
        float inv = rsqrtf(var + 1e-5f);
        float g = gamma[t] * inv;
        s_scale[t] = g;
        s_shift[t] = beta[t] - mean * g;
    }
    __syncthreads();
    int idx = blockIdx.x * 256 + t;
    if (idx < total) {
        int col = idx % PA;
        out[idx] = logits[idx] * s_scale[col] + s_shift[col];
    }
}

// ------------------- launch -------------------
extern "C" void kernel_launch(void* const* d_in, const int* in_sizes, int n_in,
                              void* d_out, int out_size, void* d_ws, size_t ws_size,
                              hipStream_t stream) {
    const float* x       = (const float*)d_in[0];
    const float* W_embed = (const float*)d_in[1];
    const float* b_embed = (const float*)d_in[2];
    const float* W_attr  = (const float*)d_in[3];
    const float* b_attr  = (const float*)d_in[4];
    const float* gamma   = (const float*)d_in[5];
    const float* beta    = (const float*)d_in[6];
    float* out = (float*)d_out;

    char* ws = (char*)d_ws;
    float* wc32   = (float*)(ws);                  // 64*768*4 = 196608
    float* bc     = (float*)(ws + 196608);         // 64*4     = 256
    float* stats  = (float*)(ws + 196864);         // 128*4    = 512
    float* logits = (float*)(ws + 197376);         // 16384*51*4 = 3342336

    init_kernel<<<13, 256, 0, stream>>>(W_attr, b_embed, b_attr, wc32, bc, stats);
    wcomb_kernel<<<192, 256, 0, stream>>>(W_embed, W_attr, wc32);
    skinny_gemm_kernel<<<512, 256, 0, stream>>>(x, wc32, bc, logits, stats);
    bn_finalize_kernel<<<3264, 256, 0, stream>>>(logits, stats, gamma, beta, out, PM * PA);
}